// Round 4
// baseline (133.939 us; speedup 1.0000x reference)
//
#include <hip/hip_runtime.h>
#include <math.h>

// Problem constants (setup_inputs): data1/data2 = (2, 4, 4096, 3) fp32, dim = 0.
constexpr int kB    = 2;
constexpr int kT    = 4;
constexpr int kBT   = kB * kT;      // 8 (b,t) slices
constexpr int kN    = 4096;         // points per slice (both sets)
constexpr int kBLK  = 256;          // threads per block
constexpr int kR    = 4;            // set1 points per thread-slot (q2 amortization)
constexpr int kP1   = 32;           // distinct set1 points per block
constexpr int kCHK  = kN / kP1;     // 128 set1 chunks per bt slice
constexpr int kREP  = kBLK * kR / kP1;  // 32 d2-replicas (rep = tid>>3)
constexpr int kD2T  = kN / kREP;    // 128 data2 points per thread
constexpr int kNG   = kD2T / 4;     // 32 groups of 4 data2 points (3 float4 each)
constexpr int kGRID = kBT * kCHK;   // 1024 blocks

// Budget model (rounds 0-3): ~40 us poison fill (fixed, 82-86% HBM peak) +
// ~11 us our kernels + ~20 us harness resets. R1 (2x occupancy) and R3
// (-9% VALU/pair) were both nulls -> instruction/occupancy levers exhausted;
// this round removes the hd_final DISPATCH via a last-block-done finish.
//
// Counter trick: ws is re-poisoned by the harness each iteration with a
// fill pattern (period <= 16 B). wsU[2048] (counter) and wsU[2052] (ref,
// 16 B away, never written) therefore start EQUAL. Each block atomicAdds 1
// to the counter; the unique block whose returned old == ref + (kGRID-1)
// is the last arrival -> it acquires and reduces the 1024 partials.
// Exactly-one guarantee: atomic returns are unique. No spin, no
// co-residency assumption, works for ANY uniform fill value.
__global__ __launch_bounds__(kBLK, 4) void hd_fused(
    const float* __restrict__ d1, const float* __restrict__ d2,
    float* __restrict__ ws, float* __restrict__ out)
{
    const int blk   = blockIdx.x;
    const int bt    = blk >> 7;            // 0..7
    const int cbase = (blk & 127) * kP1;   // set1 chunk base within slice
    const int tid   = threadIdx.x;
    const int pset  = tid & 7;
    const int rep   = tid >> 3;

    // ---------------- phase 1: proven R2 core (kR=4) ----------------
    const float* __restrict__ base1 = d1 + (size_t)bt * kN * 3;
    float nx[kR], ny[kR], nz[kR], m[kR];
#pragma unroll
    for (int k = 0; k < kR; ++k) {
        const int p = cbase + pset * 4 + k;
        const float x = base1[p * 3 + 0];
        const float y = base1[p * 3 + 1];
        const float z = base1[p * 3 + 2];
        nx[k] = -2.0f * x; ny[k] = -2.0f * y; nz[k] = -2.0f * z;
        m[k]  = 3.402823466e38f;
    }

    // This thread's data2 slice: 128 pts * 3 floats = 96 float4, 16B aligned.
    const float4* __restrict__ g2 =
        (const float4*)(d2 + (size_t)bt * kN * 3 + (size_t)rep * kD2T * 3);

#pragma unroll 4
    for (int g = 0; g < kNG; ++g) {
        const float4 A  = g2[3 * g + 0];
        const float4 Bv = g2[3 * g + 1];
        const float4 Cv = g2[3 * g + 2];
        const float px[4] = {A.x, A.w, Bv.z, Cv.y};
        const float py[4] = {A.y, Bv.x, Bv.w, Cv.z};
        const float pz[4] = {A.z, Bv.y, Cv.x, Cv.w};
        float s[4][kR];
#pragma unroll
        for (int j = 0; j < 4; ++j) {
            const float q2 = fmaf(px[j], px[j], fmaf(py[j], py[j], pz[j] * pz[j]));
#pragma unroll
            for (int k = 0; k < kR; ++k) {
                float t = fmaf(px[j], nx[k], q2);
                t = fmaf(py[j], ny[k], t);
                s[j][k] = fmaf(pz[j], nz[k], t);
            }
        }
#pragma unroll
        for (int k = 0; k < kR; ++k) {
            m[k] = fminf(m[k], fminf(s[0][k], s[1][k]));
            m[k] = fminf(m[k], fminf(s[2][k], s[3][k]));
        }
    }

    // Combine the 32 replicas: butterfly over lane bits 3..5, then 4-wave LDS.
#pragma unroll
    for (int off = 8; off <= 32; off <<= 1) {
#pragma unroll
        for (int k = 0; k < kR; ++k)
            m[k] = fminf(m[k], __shfl_xor(m[k], off, 64));
    }

    __shared__ float ls[4][kP1];          // [wave][point-in-chunk]
    const int lane = tid & 63;
    const int wav  = tid >> 6;
    if (lane < 8) {
#pragma unroll
        for (int k = 0; k < kR; ++k) ls[wav][lane * 4 + k] = m[k];
    }
    __syncthreads();

    __shared__ int lastFlag;              // single writer (tid 0) before sync
    if (tid < kP1) {
        const float v = fminf(fminf(ls[0][tid], ls[1][tid]),
                              fminf(ls[2][tid], ls[3][tid]));
        const int p = cbase + tid;
        const float x = base1[p * 3 + 0];
        const float y = base1[p * 3 + 1];
        const float z = base1[p * 3 + 2];
        const float q1 = fmaf(x, x, fmaf(y, y, z * z));
        float sum = sqrtf(fmaxf(v + q1, 0.0f));
#pragma unroll
        for (int off = 16; off >= 1; off >>= 1)
            sum += __shfl_down(sum, off, 64);
        if (tid == 0) {
            ws[blk] = sum;                             // plain store (release below)
            __threadfence();                           // order store before atomic
            volatile unsigned* wsU = (volatile unsigned*)ws;
            const unsigned ref = wsU[2052];            // untouched poison word
            const unsigned old =
                atomicAdd((unsigned*)ws + 2048, 1u);   // arrival counter
            lastFlag = (old == ref + (unsigned)(kGRID - 1)) ? 1 : 0;
        }
    }
    __syncthreads();

    // ---------------- phase 2: unique last block finishes ----------------
    if (lastFlag) {                                    // block-uniform branch
        __threadfence();                               // acquire all partials
        const float4* __restrict__ w4 = (const float4*)ws;
        const float4 v = w4[tid];                      // tid<256 covers ws[0..1023]
        const float s = (v.x + v.y) + (v.z + v.w);
        float a = (tid < 128) ? s : 0.0f;              // blocks 0..511  -> out[0]
        float b = (tid < 128) ? 0.0f : s;              // blocks 512..1023 -> out[1]
#pragma unroll
        for (int off = 32; off >= 1; off >>= 1) {
            a += __shfl_down(a, off, 64);
            b += __shfl_down(b, off, 64);
        }
        __shared__ float la[4], lb[4];
        if ((tid & 63) == 0) { la[tid >> 6] = a; lb[tid >> 6] = b; }
        __syncthreads();
        if (tid == 0) {
            const float scale = 1.0f / (kT * kN);
            out[0] = (la[0] + la[1] + la[2] + la[3]) * scale;
            out[1] = (lb[0] + lb[1] + lb[2] + lb[3]) * scale;
        }
    }
}

extern "C" void kernel_launch(void* const* d_in, const int* in_sizes, int n_in,
                              void* d_out, int out_size, void* d_ws, size_t ws_size,
                              hipStream_t stream) {
    const float* d1 = (const float*)d_in[0];
    const float* d2 = (const float*)d_in[1];
    // d_in[2] is dim == 0 -> identity swapaxes; ignored.
    float* out = (float*)d_out;
    float* ws = (float*)d_ws;

    hd_fused<<<dim3(kGRID), dim3(kBLK), 0, stream>>>(d1, d2, ws, out);
}

// Round 5
// 71.580 us; speedup vs baseline: 1.8712x; 1.8712x over previous
//
#include <hip/hip_runtime.h>
#include <math.h>

// Problem constants (setup_inputs): data1/data2 = (2, 4, 4096, 3) fp32, dim = 0.
constexpr int kB    = 2;
constexpr int kT    = 4;
constexpr int kBT   = kB * kT;      // 8 (b,t) slices
constexpr int kN    = 4096;         // points per slice (both sets)
constexpr int kBLK  = 256;          // threads per block
constexpr int kR    = 4;            // set1 points per thread-slot (q2 amortization)
constexpr int kP1   = 32;           // distinct set1 points per block
constexpr int kCHK  = kN / kP1;     // 128 set1 chunks per bt slice
constexpr int kREP  = kBLK * kR / kP1;  // 32 d2-replicas (rep = tid>>3)
constexpr int kD2T  = kN / kREP;    // 128 data2 points per thread
constexpr int kNG   = kD2T / 4;     // 32 groups of 4 data2 points (3 float4 each)

// Budget model (rounds 0-4): ~40 us poison fill (fixed, 82-86% HBM peak,
// stream-ordered before us) + ~20 us harness reset dispatches + ~11 us our
// kernels. R1 (2x occupancy) and R3 (-9% VALU/pair) were nulls; R4's fused
// last-block finish REGRESSED 61 us (per-block device-scope fences/atomics
// serialize at the coherence point on multi-XCD gfx950 — never fence O(grid)
// times). This is the proven R2 structure: best measured 73.0 us.
//
// Single compute kernel: one block per (bt, 32-point set1 chunk); the block
// sweeps ALL 4096 data2 points (split 32 ways across thread-replicas) -> no
// partial-min matrix, no 8 MB ws traffic.
//
// Thread layout: pset = tid&7 owns set1 points chunkBase + pset*4 + k
// (k<4, 32x replicated); rep = tid>>3 owns data2 slice [rep*128, rep*128+128).
// The 8 wave-replicas of a pset differ in lane bits 3..5 -> butterfly over
// 8,16,32; then a 4-wave LDS combine (512 B).
//
// Inner math: s = q2 - 2*dot (set1 pre-scaled by -2 for the fma form), q1
// added once in the epilogue. 4.25 VALU instr/pair, zero LDS in the loop.
__global__ __launch_bounds__(kBLK, 4) void hd_main(
    const float* __restrict__ d1, const float* __restrict__ d2,
    float* __restrict__ ws)
{
    const int blk  = blockIdx.x;
    const int bt   = blk >> 7;            // 0..7
    const int cbase = (blk & 127) * kP1;  // set1 chunk base within slice
    const int tid  = threadIdx.x;
    const int pset = tid & 7;
    const int rep  = tid >> 3;

    // Per-thread set1 points (registers), pre-scaled by -2 for the fma form.
    const float* __restrict__ base1 = d1 + (size_t)bt * kN * 3;
    float nx[kR], ny[kR], nz[kR], m[kR];
#pragma unroll
    for (int k = 0; k < kR; ++k) {
        const int p = cbase + pset * 4 + k;
        const float x = base1[p * 3 + 0];
        const float y = base1[p * 3 + 1];
        const float z = base1[p * 3 + 2];
        nx[k] = -2.0f * x; ny[k] = -2.0f * y; nz[k] = -2.0f * z;
        m[k]  = 3.402823466e38f;
    }

    // This thread's data2 slice: 128 pts * 3 floats = 96 float4, 16B aligned
    // (bt*12288 and rep*384 floats are multiples of 4). 8 lanes share each
    // address -> one 128B-useful load instr per float4 across the wave.
    const float4* __restrict__ g2 =
        (const float4*)(d2 + (size_t)bt * kN * 3 + (size_t)rep * kD2T * 3);

#pragma unroll 4
    for (int g = 0; g < kNG; ++g) {
        const float4 A  = g2[3 * g + 0];
        const float4 Bv = g2[3 * g + 1];
        const float4 Cv = g2[3 * g + 2];
        const float px[4] = {A.x, A.w, Bv.z, Cv.y};
        const float py[4] = {A.y, Bv.x, Bv.w, Cv.z};
        const float pz[4] = {A.z, Bv.y, Cv.x, Cv.w};
        float s[4][kR];
#pragma unroll
        for (int j = 0; j < 4; ++j) {
            const float q2 = fmaf(px[j], px[j], fmaf(py[j], py[j], pz[j] * pz[j]));
#pragma unroll
            for (int k = 0; k < kR; ++k) {
                float t = fmaf(px[j], nx[k], q2);
                t = fmaf(py[j], ny[k], t);
                s[j][k] = fmaf(pz[j], nz[k], t);
            }
        }
        // v_min3 formation: 2 three-input mins per k per group.
#pragma unroll
        for (int k = 0; k < kR; ++k) {
            m[k] = fminf(m[k], fminf(s[0][k], s[1][k]));
            m[k] = fminf(m[k], fminf(s[2][k], s[3][k]));
        }
    }

    // Combine the 32 replicas. Within a wave the 8 replicas of a pset differ
    // in lane bits 3..5 -> butterfly over 8,16,32.
#pragma unroll
    for (int off = 8; off <= 32; off <<= 1) {
#pragma unroll
        for (int k = 0; k < kR; ++k)
            m[k] = fminf(m[k], __shfl_xor(m[k], off, 64));
    }

    __shared__ float ls[4][kP1];          // [wave][point-in-chunk]
    const int lane = tid & 63;
    const int wav  = tid >> 6;
    if (lane < 8) {
#pragma unroll
        for (int k = 0; k < kR; ++k) ls[wav][lane * 4 + k] = m[k];
    }
    __syncthreads();

    // First 32 threads: cross-wave min for set1 point (cbase + tid), add q1,
    // sqrt, then sum the 32 distances and emit one partial per block.
    float sum = 0.0f;
    if (tid < kP1) {
        const float v = fminf(fminf(ls[0][tid], ls[1][tid]),
                              fminf(ls[2][tid], ls[3][tid]));
        const int p = cbase + tid;
        const float x = base1[p * 3 + 0];
        const float y = base1[p * 3 + 1];
        const float z = base1[p * 3 + 2];
        const float q1 = fmaf(x, x, fmaf(y, y, z * z));
        sum = sqrtf(fmaxf(v + q1, 0.0f));
#pragma unroll
        for (int off = 16; off >= 1; off >>= 1)
            sum += __shfl_down(sum, off, 64);
        if (tid == 0) ws[blk] = sum;      // plain store, no atomics, no fences
    }
}

// Finisher: one block, 1024 threads; ws[0..511] -> out[0], ws[512..1023] ->
// out[1]. Plain stores -> no zero-init of out needed (poison overwritten).
// Kept as a separate ~2 us dispatch: R4 proved in-kernel finishing via
// per-block device fences costs ~70 us on multi-XCD gfx950.
__global__ __launch_bounds__(1024) void hd_final(
    const float* __restrict__ ws, float* __restrict__ out)
{
    const int tid = threadIdx.x;
    float sum = ws[tid];
#pragma unroll
    for (int off = 32; off >= 1; off >>= 1)
        sum += __shfl_down(sum, off, 64);

    __shared__ float ls[16];
    if ((tid & 63) == 0) ls[tid >> 6] = sum;
    __syncthreads();
    if (tid == 0) {
        float a = 0.0f, b = 0.0f;
#pragma unroll
        for (int w = 0; w < 8; ++w) { a += ls[w]; b += ls[w + 8]; }
        const float scale = 1.0f / (kT * kN);
        out[0] = a * scale;
        out[1] = b * scale;
    }
}

extern "C" void kernel_launch(void* const* d_in, const int* in_sizes, int n_in,
                              void* d_out, int out_size, void* d_ws, size_t ws_size,
                              hipStream_t stream) {
    const float* d1 = (const float*)d_in[0];
    const float* d2 = (const float*)d_in[1];
    // d_in[2] is dim == 0 -> identity swapaxes; ignored.
    float* out = (float*)d_out;
    float* ws = (float*)d_ws;

    hd_main<<<dim3(kBT * kCHK), dim3(kBLK), 0, stream>>>(d1, d2, ws);
    hd_final<<<dim3(1), dim3(1024), 0, stream>>>(ws, out);
}